// Round 1
// baseline (1606.763 us; speedup 1.0000x reference)
//
#include <hip/hip_runtime.h>
#include <stdint.h>

#define TPB 512
#define NJ 16          // float4 chunks per thread: 512*16*4 = 32768 = H
#define HSZ 32768

// order-preserving float->uint key: bigger float => bigger key
__device__ __forceinline__ uint32_t f2k(float f) {
    uint32_t u = __float_as_uint(f);
    uint32_t m = 0x80000000u | (uint32_t)(-(int32_t)(u >> 31));
    return u ^ m;
}

__global__ __launch_bounds__(TPB, 4) void topk_scatter_kernel(
    const float* __restrict__ x,
    const int* __restrict__ kp,
    float* __restrict__ out)
{
    __shared__ uint32_t hist[4096];
    __shared__ uint32_t suf[TPB];
    __shared__ uint32_t sh_bin1, sh_rem1, sh_bin2, sh_rem2;
    __shared__ uint32_t sh_bin3, sh_eqneed, sh_eqcnt;
    __shared__ uint32_t wave_tot[TPB / 64];
    __shared__ uint32_t chunk_base;

    const int t = threadIdx.x;
    const size_t row = blockIdx.x;
    const float* xr = x + row * (size_t)HSZ;
    float* outr = out + row * (size_t)HSZ;

    // ---- single HBM read: row -> registers ----
    float4 vv[NJ];
#pragma unroll
    for (int j = 0; j < NJ; ++j)
        vv[j] = reinterpret_cast<const float4*>(xr)[j * TPB + t];

    const uint32_t k = (uint32_t)kp[0];

    if (k == 0u) {  // degenerate: all zeros
        float4 z; z.x = z.y = z.z = z.w = 0.0f;
#pragma unroll
        for (int j = 0; j < NJ; ++j)
            reinterpret_cast<float4*>(outr)[j * TPB + t] = z;
        return;
    }

    // =========== Level 1: key bits [31:20], 4096 bins ===========
    for (int i = t; i < 4096; i += TPB) hist[i] = 0u;
    __syncthreads();
#pragma unroll
    for (int j = 0; j < NJ; ++j) {
        float vals[4] = { vv[j].x, vv[j].y, vv[j].z, vv[j].w };
#pragma unroll
        for (int c = 0; c < 4; ++c)
            atomicAdd(&hist[f2k(vals[c]) >> 20], 1u);
    }
    __syncthreads();
    {
        const uint32_t need = k;
        uint32_t s = 0;
#pragma unroll
        for (int jj = 0; jj < 8; ++jj) s += hist[t * 8 + jj];
        suf[t] = s;
        __syncthreads();
        for (int off = 1; off < TPB; off <<= 1) {
            uint32_t a = suf[t];
            uint32_t b = (t + off < TPB) ? suf[t + off] : 0u;
            __syncthreads();
            suf[t] = a + b;
            __syncthreads();
        }
        const uint32_t myS = suf[t];
        const uint32_t hiS = (t < TPB - 1) ? suf[t + 1] : 0u;
        if (myS >= need && hiS < need) {
            uint32_t run = hiS;
#pragma unroll
            for (int jj = 7; jj >= 0; --jj) {
                uint32_t c = hist[t * 8 + jj];
                if (run + c >= need) { sh_bin1 = (uint32_t)(t * 8 + jj); sh_rem1 = need - run; break; }
                run += c;
            }
        }
        __syncthreads();
    }
    const uint32_t B1 = sh_bin1;
    const uint32_t need2 = sh_rem1;

    // =========== Level 2: key bits [19:8], 4096 bins ===========
    for (int i = t; i < 4096; i += TPB) hist[i] = 0u;
    __syncthreads();
#pragma unroll
    for (int j = 0; j < NJ; ++j) {
        float vals[4] = { vv[j].x, vv[j].y, vv[j].z, vv[j].w };
#pragma unroll
        for (int c = 0; c < 4; ++c) {
            uint32_t key = f2k(vals[c]);
            if ((key >> 20) == B1) atomicAdd(&hist[(key >> 8) & 0xFFFu], 1u);
        }
    }
    __syncthreads();
    {
        const uint32_t need = need2;
        uint32_t s = 0;
#pragma unroll
        for (int jj = 0; jj < 8; ++jj) s += hist[t * 8 + jj];
        suf[t] = s;
        __syncthreads();
        for (int off = 1; off < TPB; off <<= 1) {
            uint32_t a = suf[t];
            uint32_t b = (t + off < TPB) ? suf[t + off] : 0u;
            __syncthreads();
            suf[t] = a + b;
            __syncthreads();
        }
        const uint32_t myS = suf[t];
        const uint32_t hiS = (t < TPB - 1) ? suf[t + 1] : 0u;
        if (myS >= need && hiS < need) {
            uint32_t run = hiS;
#pragma unroll
            for (int jj = 7; jj >= 0; --jj) {
                uint32_t c = hist[t * 8 + jj];
                if (run + c >= need) { sh_bin2 = (uint32_t)(t * 8 + jj); sh_rem2 = need - run; break; }
                run += c;
            }
        }
        __syncthreads();
    }
    const uint32_t B2 = sh_bin2;
    const uint32_t need3 = sh_rem2;

    // =========== Level 3: key bits [7:0], 256 bins ===========
    if (t < 256) hist[t] = 0u;
    __syncthreads();
    const uint32_t pref = (B1 << 12) | B2;  // top 24 bits of key
#pragma unroll
    for (int j = 0; j < NJ; ++j) {
        float vals[4] = { vv[j].x, vv[j].y, vv[j].z, vv[j].w };
#pragma unroll
        for (int c = 0; c < 4; ++c) {
            uint32_t key = f2k(vals[c]);
            if ((key >> 8) == pref) atomicAdd(&hist[key & 0xFFu], 1u);
        }
    }
    __syncthreads();
    {
        const uint32_t need = need3;
        if (t < 256) suf[t] = hist[t];
        __syncthreads();
        for (int off = 1; off < 256; off <<= 1) {
            uint32_t a = 0u, b = 0u;
            if (t < 256) { a = suf[t]; b = (t + off < 256) ? suf[t + off] : 0u; }
            __syncthreads();
            if (t < 256) suf[t] = a + b;
            __syncthreads();
        }
        if (t < 256) {
            uint32_t myS = suf[t];
            uint32_t hiS = (t < 255) ? suf[t + 1] : 0u;
            if (myS >= need && hiS < need) {
                sh_bin3 = (uint32_t)t;
                sh_eqneed = need - hiS;
                sh_eqcnt = hist[t];
            }
        }
        __syncthreads();
    }
    const uint32_t B3 = sh_bin3;
    const uint32_t K = (B1 << 20) | (B2 << 8) | B3;
    const uint32_t eqneed = sh_eqneed;
    const uint32_t eqcnt = sh_eqcnt;

    // =========== Output pass ===========
    if (eqcnt == eqneed) {
        // all elements equal to K are selected: out = (key >= K) ? v : 0
#pragma unroll
        for (int j = 0; j < NJ; ++j) {
            float vals[4] = { vv[j].x, vv[j].y, vv[j].z, vv[j].w };
            float ov[4];
#pragma unroll
            for (int c = 0; c < 4; ++c)
                ov[c] = (f2k(vals[c]) >= K) ? vals[c] : 0.0f;
            float4 o; o.x = ov[0]; o.y = ov[1]; o.z = ov[2]; o.w = ov[3];
            reinterpret_cast<float4*>(outr)[j * TPB + t] = o;
        }
    } else {
        // rare: more elements == K than slots; take lowest column indices.
        // column of (j,t,c) = j*2048 + t*4 + c -> lexicographic (j,t,c) order.
        if (t == 0) chunk_base = 0u;
        __syncthreads();
        const int lane = t & 63;
        const int wid = t >> 6;
#pragma unroll
        for (int j = 0; j < NJ; ++j) {
            float vals[4] = { vv[j].x, vv[j].y, vv[j].z, vv[j].w };
            uint32_t keys[4];
            uint32_t e = 0;
#pragma unroll
            for (int c = 0; c < 4; ++c) { keys[c] = f2k(vals[c]); e += (keys[c] == K) ? 1u : 0u; }
            // wave-inclusive scan of e
            uint32_t pre = e;
            for (int off = 1; off < 64; off <<= 1) {
                uint32_t n = (uint32_t)__shfl_up((int)pre, off, 64);
                if (lane >= off) pre += n;
            }
            if (lane == 63) wave_tot[wid] = pre;
            __syncthreads();
            uint32_t before = chunk_base + (pre - e);
            for (int w = 0; w < wid; ++w) before += wave_tot[w];
            float ov[4];
#pragma unroll
            for (int c = 0; c < 4; ++c) {
                bool take = keys[c] > K;
                if (keys[c] == K) { take = (before < eqneed); ++before; }
                ov[c] = take ? vals[c] : 0.0f;
            }
            float4 o; o.x = ov[0]; o.y = ov[1]; o.z = ov[2]; o.w = ov[3];
            reinterpret_cast<float4*>(outr)[j * TPB + t] = o;
            __syncthreads();
            if (t == 0) {
                uint32_t s2 = chunk_base;
#pragma unroll
                for (int w = 0; w < TPB / 64; ++w) s2 += wave_tot[w];
                chunk_base = s2;
            }
            __syncthreads();
        }
    }
}

extern "C" void kernel_launch(void* const* d_in, const int* in_sizes, int n_in,
                              void* d_out, int out_size, void* d_ws, size_t ws_size,
                              hipStream_t stream) {
    const float* x = (const float*)d_in[0];
    const int* kp = (const int*)d_in[1];
    float* out = (float*)d_out;
    const int total = in_sizes[0];
    const int rows = total / HSZ;   // 8192
    topk_scatter_kernel<<<rows, TPB, 0, stream>>>(x, kp, out);
}

// Round 2
// 533.434 us; speedup vs baseline: 3.0121x; 3.0121x over previous
//
#include <hip/hip_runtime.h>
#include <stdint.h>

#define TPB 512
#define NJ 16          // float4 chunks per thread: 512*16*4 = 32768 = H
#define HSZ 32768
#define CAP 2048       // candidate capacity (bin at threshold ~25 elems for N(0,1))

// order-preserving float->uint key: bigger float => bigger key
__device__ __forceinline__ uint32_t f2k(float f) {
    uint32_t u = __float_as_uint(f);
    return u ^ (0x80000000u | (uint32_t)(-(int32_t)(u >> 31)));
}
__device__ __forceinline__ float k2f(uint32_t key) {
    uint32_t u = (key & 0x80000000u) ? (key ^ 0x80000000u) : ~key;
    return __uint_as_float(u);
}

// Suffix-select over hist[4096] (bins descending = larger values).
// Finds bin B s.t. count(bins > B) < need <= count(bins >= B).
// Writes *sh_bin = B, *sh_rem = need - count(bins > B). All threads call.
__device__ __forceinline__ void select4096(const uint32_t* hist, uint32_t need,
                                           uint32_t* wtot, uint32_t* sh_bin,
                                           uint32_t* sh_rem, int t) {
    const int lane = t & 63, wid = t >> 6;
    uint32_t b[8], pt = 0;
#pragma unroll
    for (int jj = 0; jj < 8; ++jj) { b[jj] = hist[t * 8 + jj]; pt += b[jj]; }
    uint32_t pre = pt;  // wave suffix-inclusive scan
#pragma unroll
    for (int off = 1; off < 64; off <<= 1) {
        uint32_t n = (uint32_t)__shfl_down((int)pre, off, 64);
        if (lane + off < 64) pre += n;
    }
    if (lane == 0) wtot[wid] = pre;
    __syncthreads();
    uint32_t wsuf = 0;
    for (int w = wid + 1; w < TPB / 64; ++w) wsuf += wtot[w];
    const uint32_t Sincl = pre + wsuf;
    const uint32_t Sexcl = Sincl - pt;
    if (Sexcl < need && Sincl >= need) {
        uint32_t run = Sexcl;
#pragma unroll
        for (int jj = 7; jj >= 0; --jj) {
            if (run + b[jj] >= need) { *sh_bin = (uint32_t)(t * 8 + jj); *sh_rem = need - run; break; }
            run += b[jj];
        }
    }
    __syncthreads();
}

// Same over hist[256]; also reports eq-bin count.
__device__ __forceinline__ void select256(const uint32_t* hist, uint32_t need,
                                          uint32_t* wtot, uint32_t* sh_bin,
                                          uint32_t* sh_rem, uint32_t* sh_eqcnt, int t) {
    const int lane = t & 63, wid = t >> 6;
    uint32_t pt = (t < 256) ? hist[t] : 0u;
    uint32_t pre = pt;
#pragma unroll
    for (int off = 1; off < 64; off <<= 1) {
        uint32_t n = (uint32_t)__shfl_down((int)pre, off, 64);
        if (lane + off < 64) pre += n;
    }
    if (lane == 0) wtot[wid] = pre;
    __syncthreads();
    uint32_t wsuf = 0;
    for (int w = wid + 1; w < TPB / 64; ++w) wsuf += wtot[w];
    const uint32_t Sincl = pre + wsuf;
    const uint32_t Sexcl = Sincl - pt;
    if (t < 256 && Sexcl < need && Sincl >= need) {
        *sh_bin = (uint32_t)t; *sh_rem = need - Sexcl; *sh_eqcnt = pt;
    }
    __syncthreads();
}

__global__ __launch_bounds__(TPB, 4) void topk_scatter_kernel(
    const float* __restrict__ x,
    const int* __restrict__ kp,
    float* __restrict__ out)
{
    __shared__ uint32_t hist[4096];
    __shared__ uint32_t wtot[TPB / 64];
    __shared__ uint32_t cand_key[CAP];
    __shared__ uint32_t cand_col[CAP];
    __shared__ uint32_t sh_bin, sh_rem, sh_eqcnt, sh_ncand;
    __shared__ uint32_t chunk_base;

    const int t = threadIdx.x;
    const size_t row = blockIdx.x;
    const float* xr = x + row * (size_t)HSZ;
    float* outr = out + row * (size_t)HSZ;
    const uint32_t k = (uint32_t)kp[0];

    if (k == 0u || k >= (uint32_t)HSZ) {  // degenerate
#pragma unroll 4
        for (int j = 0; j < NJ; ++j) {
            float4 o;
            if (k == 0u) { o.x = o.y = o.z = o.w = 0.0f; }
            else o = reinterpret_cast<const float4*>(xr)[j * TPB + t];
            reinterpret_cast<float4*>(outr)[j * TPB + t] = o;
        }
        return;
    }

    // ===== Pass 1: stream row, level-1 histogram (key bits [31:20]) =====
    for (int i = t; i < 4096; i += TPB) hist[i] = 0u;
    if (t == 0) sh_ncand = 0u;
    __syncthreads();
#pragma unroll 4
    for (int j = 0; j < NJ; ++j) {
        float4 v = reinterpret_cast<const float4*>(xr)[j * TPB + t];
        atomicAdd(&hist[f2k(v.x) >> 20], 1u);
        atomicAdd(&hist[f2k(v.y) >> 20], 1u);
        atomicAdd(&hist[f2k(v.z) >> 20], 1u);
        atomicAdd(&hist[f2k(v.w) >> 20], 1u);
    }
    __syncthreads();
    select4096(hist, k, wtot, &sh_bin, &sh_rem, t);
    const uint32_t B1 = sh_bin;
    const uint32_t need2 = sh_rem;

    // ===== Pass 2: re-read (LLC-hot), write provisional output, compact =====
#pragma unroll 4
    for (int j = 0; j < NJ; ++j) {
        float4 v = reinterpret_cast<const float4*>(xr)[j * TPB + t];
        float vals[4] = { v.x, v.y, v.z, v.w };
        float ov[4];
#pragma unroll
        for (int c = 0; c < 4; ++c) {
            uint32_t key = f2k(vals[c]);
            uint32_t b = key >> 20;
            ov[c] = (b > B1) ? vals[c] : 0.0f;
            if (b == B1) {
                uint32_t pos = atomicAdd(&sh_ncand, 1u);
                if (pos < CAP) {
                    cand_key[pos] = key;
                    cand_col[pos] = (uint32_t)((j * TPB + t) * 4 + c);
                }
            }
        }
        float4 o; o.x = ov[0]; o.y = ov[1]; o.z = ov[2]; o.w = ov[3];
        reinterpret_cast<float4*>(outr)[j * TPB + t] = o;
    }
    __syncthreads();
    const uint32_t C = sh_ncand;

    if (C <= CAP) {
        // ===== Refine among C candidates (tiny) =====
        // level 2: bits [19:8]
        for (int i = t; i < 4096; i += TPB) hist[i] = 0u;
        __syncthreads();
        for (uint32_t i = t; i < C; i += TPB)
            atomicAdd(&hist[(cand_key[i] >> 8) & 0xFFFu], 1u);
        __syncthreads();
        select4096(hist, need2, wtot, &sh_bin, &sh_rem, t);
        const uint32_t B2 = sh_bin;
        const uint32_t need3 = sh_rem;

        // level 3: bits [7:0]
        if (t < 256) hist[t] = 0u;
        __syncthreads();
        const uint32_t pref = (B1 << 12) | B2;
        for (uint32_t i = t; i < C; i += TPB)
            if ((cand_key[i] >> 8) == pref) atomicAdd(&hist[cand_key[i] & 0xFFu], 1u);
        __syncthreads();
        select256(hist, need3, wtot, &sh_bin, &sh_rem, &sh_eqcnt, t);
        const uint32_t K = (pref << 8) | sh_bin;
        const uint32_t eqneed = sh_rem;
        const uint32_t eqcnt = sh_eqcnt;

        // scatter selected candidates over the provisional zeros
        for (uint32_t i = t; i < C; i += TPB) {
            uint32_t key = cand_key[i];
            if (key > K) {
                outr[cand_col[i]] = k2f(key);
            } else if (key == K) {
                if (eqcnt == eqneed) {
                    outr[cand_col[i]] = k2f(key);
                } else {
                    // exact tie-break: lowest columns win
                    uint32_t rank = 0, col = cand_col[i];
                    for (uint32_t m = 0; m < C; ++m)
                        if (cand_key[m] == K && cand_col[m] < col) ++rank;
                    if (rank < eqneed) outr[cand_col[i]] = k2f(key);
                }
            }
        }
    } else {
        // ===== Fallback (candidate overflow — never for Gaussian data) =====
        // level 2 from global
        for (int i = t; i < 4096; i += TPB) hist[i] = 0u;
        __syncthreads();
        for (int j = 0; j < NJ; ++j) {
            float4 v = reinterpret_cast<const float4*>(xr)[j * TPB + t];
            float vals[4] = { v.x, v.y, v.z, v.w };
#pragma unroll
            for (int c = 0; c < 4; ++c) {
                uint32_t key = f2k(vals[c]);
                if ((key >> 20) == B1) atomicAdd(&hist[(key >> 8) & 0xFFFu], 1u);
            }
        }
        __syncthreads();
        select4096(hist, need2, wtot, &sh_bin, &sh_rem, t);
        const uint32_t B2 = sh_bin;
        const uint32_t need3 = sh_rem;

        // level 3 from global
        if (t < 256) hist[t] = 0u;
        __syncthreads();
        const uint32_t pref = (B1 << 12) | B2;
        for (int j = 0; j < NJ; ++j) {
            float4 v = reinterpret_cast<const float4*>(xr)[j * TPB + t];
            float vals[4] = { v.x, v.y, v.z, v.w };
#pragma unroll
            for (int c = 0; c < 4; ++c) {
                uint32_t key = f2k(vals[c]);
                if ((key >> 8) == pref) atomicAdd(&hist[key & 0xFFu], 1u);
            }
        }
        __syncthreads();
        select256(hist, need3, wtot, &sh_bin, &sh_rem, &sh_eqcnt, t);
        const uint32_t K = (pref << 8) | sh_bin;
        const uint32_t eqneed = sh_rem;
        const uint32_t eqcnt = sh_eqcnt;

        if (eqcnt == eqneed) {
            for (int j = 0; j < NJ; ++j) {
                float4 v = reinterpret_cast<const float4*>(xr)[j * TPB + t];
                float vals[4] = { v.x, v.y, v.z, v.w };
                float ov[4];
#pragma unroll
                for (int c = 0; c < 4; ++c)
                    ov[c] = (f2k(vals[c]) >= K) ? vals[c] : 0.0f;
                float4 o; o.x = ov[0]; o.y = ov[1]; o.z = ov[2]; o.w = ov[3];
                reinterpret_cast<float4*>(outr)[j * TPB + t] = o;
            }
        } else {
            // ordered selection among ==K by lowest column, streaming chunks
            if (t == 0) chunk_base = 0u;
            __syncthreads();
            const int lane = t & 63;
            const int wid = t >> 6;
            for (int j = 0; j < NJ; ++j) {
                float4 v = reinterpret_cast<const float4*>(xr)[j * TPB + t];
                float vals[4] = { v.x, v.y, v.z, v.w };
                uint32_t keys[4];
                uint32_t e = 0;
#pragma unroll
                for (int c = 0; c < 4; ++c) { keys[c] = f2k(vals[c]); e += (keys[c] == K) ? 1u : 0u; }
                uint32_t pre = e;
                for (int off = 1; off < 64; off <<= 1) {
                    uint32_t n = (uint32_t)__shfl_up((int)pre, off, 64);
                    if (lane >= off) pre += n;
                }
                if (lane == 63) wtot[wid] = pre;
                __syncthreads();
                uint32_t before = chunk_base + (pre - e);
                for (int w = 0; w < wid; ++w) before += wtot[w];
                float ov[4];
#pragma unroll
                for (int c = 0; c < 4; ++c) {
                    bool take = keys[c] > K;
                    if (keys[c] == K) { take = (before < eqneed); ++before; }
                    ov[c] = take ? vals[c] : 0.0f;
                }
                float4 o; o.x = ov[0]; o.y = ov[1]; o.z = ov[2]; o.w = ov[3];
                reinterpret_cast<float4*>(outr)[j * TPB + t] = o;
                __syncthreads();
                if (t == 0) {
                    uint32_t s2 = chunk_base;
#pragma unroll
                    for (int w = 0; w < TPB / 64; ++w) s2 += wtot[w];
                    chunk_base = s2;
                }
                __syncthreads();
            }
        }
    }
}

extern "C" void kernel_launch(void* const* d_in, const int* in_sizes, int n_in,
                              void* d_out, int out_size, void* d_ws, size_t ws_size,
                              hipStream_t stream) {
    const float* x = (const float*)d_in[0];
    const int* kp = (const int*)d_in[1];
    float* out = (float*)d_out;
    const int total = in_sizes[0];
    const int rows = total / HSZ;   // 8192
    topk_scatter_kernel<<<rows, TPB, 0, stream>>>(x, kp, out);
}

// Round 3
// 465.568 us; speedup vs baseline: 3.4512x; 1.1458x over previous
//
#include <hip/hip_runtime.h>
#include <stdint.h>

#define TPB 1024
#define NJ 8           // float4 chunks per thread: 1024*8*4 = 32768 = H
#define HSZ 32768
#define NW (TPB / 64)  // 16 waves
#define CAP 2048       // candidate capacity (threshold bin ~30 elems for N(0,1))

// order-preserving float->uint key: bigger float => bigger key
__device__ __forceinline__ uint32_t f2k(float f) {
    uint32_t u = __float_as_uint(f);
    return u ^ (0x80000000u | (uint32_t)(-(int32_t)(u >> 31)));
}
__device__ __forceinline__ float k2f(uint32_t key) {
    uint32_t u = (key & 0x80000000u) ? (key ^ 0x80000000u) : ~key;
    return __uint_as_float(u);
}

// Suffix-select over hist[4096] (descending bins = larger values).
// Finds bin B with count(>B) < need <= count(>=B); *sh_bin=B, *sh_rem=need-count(>B).
__device__ __forceinline__ void select4096(const uint32_t* hist, uint32_t need,
                                           uint32_t* wtot, uint32_t* sh_bin,
                                           uint32_t* sh_rem, int t) {
    const int lane = t & 63, wid = t >> 6;
    uint32_t b[4], pt = 0;
#pragma unroll
    for (int jj = 0; jj < 4; ++jj) { b[jj] = hist[t * 4 + jj]; pt += b[jj]; }
    uint32_t pre = pt;  // wave suffix-inclusive scan
#pragma unroll
    for (int off = 1; off < 64; off <<= 1) {
        uint32_t n = (uint32_t)__shfl_down((int)pre, off, 64);
        if (lane + off < 64) pre += n;
    }
    if (lane == 0) wtot[wid] = pre;
    __syncthreads();
    uint32_t wsuf = 0;
    for (int w = wid + 1; w < NW; ++w) wsuf += wtot[w];
    const uint32_t Sincl = pre + wsuf;
    const uint32_t Sexcl = Sincl - pt;
    if (Sexcl < need && Sincl >= need) {
        uint32_t run = Sexcl;
#pragma unroll
        for (int jj = 3; jj >= 0; --jj) {
            if (run + b[jj] >= need) { *sh_bin = (uint32_t)(t * 4 + jj); *sh_rem = need - run; break; }
            run += b[jj];
        }
    }
    __syncthreads();
}

// Same over hist[256]; also reports count of the selected bin.
__device__ __forceinline__ void select256(const uint32_t* hist, uint32_t need,
                                          uint32_t* wtot, uint32_t* sh_bin,
                                          uint32_t* sh_rem, uint32_t* sh_eqcnt, int t) {
    const int lane = t & 63, wid = t >> 6;
    uint32_t pt = (t < 256) ? hist[t] : 0u;
    uint32_t pre = pt;
#pragma unroll
    for (int off = 1; off < 64; off <<= 1) {
        uint32_t n = (uint32_t)__shfl_down((int)pre, off, 64);
        if (lane + off < 64) pre += n;
    }
    if (lane == 0) wtot[wid] = pre;
    __syncthreads();
    uint32_t wsuf = 0;
    for (int w = wid + 1; w < NW; ++w) wsuf += wtot[w];
    const uint32_t Sincl = pre + wsuf;
    const uint32_t Sexcl = Sincl - pt;
    if (t < 256 && Sexcl < need && Sincl >= need) {
        *sh_bin = (uint32_t)t; *sh_rem = need - Sexcl; *sh_eqcnt = pt;
    }
    __syncthreads();
}

__global__ __launch_bounds__(TPB, 4) void topk_scatter_kernel(
    const float* __restrict__ x,
    const int* __restrict__ kp,
    float* __restrict__ out)
{
    __shared__ uint32_t hist[4096];
    __shared__ uint32_t wtot[NW];
    __shared__ uint32_t cand_key[CAP];
    __shared__ uint32_t cand_col[CAP];
    __shared__ uint32_t sh_bin, sh_rem, sh_eqcnt, sh_ncand;
    __shared__ uint32_t chunk_base;

    const int t = threadIdx.x;
    const size_t row = blockIdx.x;
    const float4* xr4 = reinterpret_cast<const float4*>(x + row * (size_t)HSZ);
    float* outr = out + row * (size_t)HSZ;
    float4* outr4 = reinterpret_cast<float4*>(outr);
    const uint32_t k = (uint32_t)kp[0];

    if (k == 0u || k >= (uint32_t)HSZ) {  // degenerate
#pragma unroll
        for (int j = 0; j < NJ; ++j) {
            float4 o;
            if (k == 0u) { o.x = o.y = o.z = o.w = 0.0f; }
            else o = xr4[j * TPB + t];
            outr4[j * TPB + t] = o;
        }
        return;
    }

    // ===== single HBM read: row -> registers, fused level-1 histogram =====
    float4 vv[NJ];
#pragma unroll
    for (int j = 0; j < NJ; ++j) vv[j] = xr4[j * TPB + t];

    for (int i = t; i < 4096; i += TPB) hist[i] = 0u;
    if (t == 0) sh_ncand = 0u;
    __syncthreads();
#pragma unroll
    for (int j = 0; j < NJ; ++j) {
        atomicAdd(&hist[f2k(vv[j].x) >> 20], 1u);
        atomicAdd(&hist[f2k(vv[j].y) >> 20], 1u);
        atomicAdd(&hist[f2k(vv[j].z) >> 20], 1u);
        atomicAdd(&hist[f2k(vv[j].w) >> 20], 1u);
    }
    __syncthreads();
    select4096(hist, k, wtot, &sh_bin, &sh_rem, t);
    const uint32_t B1 = sh_bin;
    const uint32_t need2 = sh_rem;

    // ===== pass 2 from registers: provisional output + candidate compaction =====
#pragma unroll
    for (int j = 0; j < NJ; ++j) {
        float vals[4] = { vv[j].x, vv[j].y, vv[j].z, vv[j].w };
        float ov[4];
#pragma unroll
        for (int c = 0; c < 4; ++c) {
            uint32_t key = f2k(vals[c]);
            uint32_t b = key >> 20;
            ov[c] = (b > B1) ? vals[c] : 0.0f;
            if (b == B1) {
                uint32_t pos = atomicAdd(&sh_ncand, 1u);
                if (pos < CAP) {
                    cand_key[pos] = key;
                    cand_col[pos] = (uint32_t)((j * TPB + t) * 4 + c);
                }
            }
        }
        float4 o; o.x = ov[0]; o.y = ov[1]; o.z = ov[2]; o.w = ov[3];
        outr4[j * TPB + t] = o;
    }
    __syncthreads();
    const uint32_t C = sh_ncand;

    if (C <= CAP) {
        // ===== refine among C candidates (tiny) =====
        // level 2: bits [19:8]
        for (int i = t; i < 4096; i += TPB) hist[i] = 0u;
        __syncthreads();
        for (uint32_t i = t; i < C; i += TPB)
            atomicAdd(&hist[(cand_key[i] >> 8) & 0xFFFu], 1u);
        __syncthreads();
        select4096(hist, need2, wtot, &sh_bin, &sh_rem, t);
        const uint32_t B2 = sh_bin;
        const uint32_t need3 = sh_rem;

        // level 3: bits [7:0]
        if (t < 256) hist[t] = 0u;
        __syncthreads();
        const uint32_t pref = (B1 << 12) | B2;
        for (uint32_t i = t; i < C; i += TPB)
            if ((cand_key[i] >> 8) == pref) atomicAdd(&hist[cand_key[i] & 0xFFu], 1u);
        __syncthreads();
        select256(hist, need3, wtot, &sh_bin, &sh_rem, &sh_eqcnt, t);
        const uint32_t K = (pref << 8) | sh_bin;
        const uint32_t eqneed = sh_rem;
        const uint32_t eqcnt = sh_eqcnt;

        // scatter selected candidates over the provisional zeros
        for (uint32_t i = t; i < C; i += TPB) {
            uint32_t key = cand_key[i];
            if (key > K) {
                outr[cand_col[i]] = k2f(key);
            } else if (key == K) {
                if (eqcnt == eqneed) {
                    outr[cand_col[i]] = k2f(key);
                } else {
                    // exact tie-break: lowest columns win
                    uint32_t rank = 0, col = cand_col[i];
                    for (uint32_t m = 0; m < C; ++m)
                        if (cand_key[m] == K && cand_col[m] < col) ++rank;
                    if (rank < eqneed) outr[cand_col[i]] = k2f(key);
                }
            }
        }
    } else {
        // ===== fallback (candidate overflow — not expected for Gaussian data) =====
        // level 2 from registers
        for (int i = t; i < 4096; i += TPB) hist[i] = 0u;
        __syncthreads();
#pragma unroll
        for (int j = 0; j < NJ; ++j) {
            float vals[4] = { vv[j].x, vv[j].y, vv[j].z, vv[j].w };
#pragma unroll
            for (int c = 0; c < 4; ++c) {
                uint32_t key = f2k(vals[c]);
                if ((key >> 20) == B1) atomicAdd(&hist[(key >> 8) & 0xFFFu], 1u);
            }
        }
        __syncthreads();
        select4096(hist, need2, wtot, &sh_bin, &sh_rem, t);
        const uint32_t B2 = sh_bin;
        const uint32_t need3 = sh_rem;

        // level 3 from registers
        if (t < 256) hist[t] = 0u;
        __syncthreads();
        const uint32_t pref = (B1 << 12) | B2;
#pragma unroll
        for (int j = 0; j < NJ; ++j) {
            float vals[4] = { vv[j].x, vv[j].y, vv[j].z, vv[j].w };
#pragma unroll
            for (int c = 0; c < 4; ++c) {
                uint32_t key = f2k(vals[c]);
                if ((key >> 8) == pref) atomicAdd(&hist[key & 0xFFu], 1u);
            }
        }
        __syncthreads();
        select256(hist, need3, wtot, &sh_bin, &sh_rem, &sh_eqcnt, t);
        const uint32_t K = (pref << 8) | sh_bin;
        const uint32_t eqneed = sh_rem;
        const uint32_t eqcnt = sh_eqcnt;

        if (eqcnt == eqneed) {
#pragma unroll
            for (int j = 0; j < NJ; ++j) {
                float vals[4] = { vv[j].x, vv[j].y, vv[j].z, vv[j].w };
                float ov[4];
#pragma unroll
                for (int c = 0; c < 4; ++c)
                    ov[c] = (f2k(vals[c]) >= K) ? vals[c] : 0.0f;
                float4 o; o.x = ov[0]; o.y = ov[1]; o.z = ov[2]; o.w = ov[3];
                outr4[j * TPB + t] = o;
            }
        } else {
            // ordered selection among ==K by lowest column, chunk-by-chunk
            if (t == 0) chunk_base = 0u;
            __syncthreads();
            const int lane = t & 63;
            const int wid = t >> 6;
            for (int j = 0; j < NJ; ++j) {
                float vals[4] = { vv[j].x, vv[j].y, vv[j].z, vv[j].w };
                uint32_t keys[4];
                uint32_t e = 0;
#pragma unroll
                for (int c = 0; c < 4; ++c) { keys[c] = f2k(vals[c]); e += (keys[c] == K) ? 1u : 0u; }
                uint32_t pre = e;
                for (int off = 1; off < 64; off <<= 1) {
                    uint32_t n = (uint32_t)__shfl_up((int)pre, off, 64);
                    if (lane >= off) pre += n;
                }
                if (lane == 63) wtot[wid] = pre;
                __syncthreads();
                uint32_t before = chunk_base + (pre - e);
                for (int w = 0; w < wid; ++w) before += wtot[w];
                float ov[4];
#pragma unroll
                for (int c = 0; c < 4; ++c) {
                    bool take = keys[c] > K;
                    if (keys[c] == K) { take = (before < eqneed); ++before; }
                    ov[c] = take ? vals[c] : 0.0f;
                }
                float4 o; o.x = ov[0]; o.y = ov[1]; o.z = ov[2]; o.w = ov[3];
                outr4[j * TPB + t] = o;
                __syncthreads();
                if (t == 0) {
                    uint32_t s2 = chunk_base;
#pragma unroll
                    for (int w = 0; w < NW; ++w) s2 += wtot[w];
                    chunk_base = s2;
                }
                __syncthreads();
            }
        }
    }
}

extern "C" void kernel_launch(void* const* d_in, const int* in_sizes, int n_in,
                              void* d_out, int out_size, void* d_ws, size_t ws_size,
                              hipStream_t stream) {
    const float* x = (const float*)d_in[0];
    const int* kp = (const int*)d_in[1];
    float* out = (float*)d_out;
    const int total = in_sizes[0];
    const int rows = total / HSZ;   // 8192
    topk_scatter_kernel<<<rows, TPB, 0, stream>>>(x, kp, out);
}